// Round 1
// baseline (792.525 us; speedup 1.0000x reference)
//
#include <hip/hip_runtime.h>

// AttFusion: per-pixel attention over L<=6 records.
// x: (16, 256, 96*288) fp32, record_len: (4,) int32, out: (4, 256, 96*288) fp32.
// Block = (batch, 32-pixel tile), 256 threads = 32 px * 8 c-groups (32 ch each).
// Pass 1: partial scores over c-range -> LDS reduce -> softmax (32 threads).
// Pass 2: re-read tile, weighted sum, store. Memory-bound; floor ~162us (2x read).

#define CC 256
#define PP (96 * 288)   // 27648
#define LMAXC 6

__global__ __launch_bounds__(256) void attfusion_kernel(
    const float* __restrict__ x, const int* __restrict__ rl,
    float* __restrict__ out)
{
    const int tid  = threadIdx.x;
    const int pxl  = tid & 31;    // pixel lane within tile
    const int grp  = tid >> 5;    // c-group 0..7
    const int tile = blockIdx.x;  // 0..863
    const int b    = blockIdx.y;  // batch
    const int px   = tile * 32 + pxl;
    const int c0   = grp * 32;

    // offsets = exclusive prefix sum of record_len (B is tiny; uniform loop)
    int off = 0;
    for (int i = 0; i < b; ++i) off += rl[i];
    int len = rl[b];
    if (len > LMAXC) len = LMAXC;
    if (len < 1)     len = 1;

    const size_t CP = (size_t)CC * PP;
    // base pointer for record 0 (= q), this thread's first channel, this pixel
    const float* p0 = x + (size_t)off * CP + (size_t)c0 * PP + (size_t)px;

    // ---- Pass 1: partial scores over this thread's 32 channels ----
    float s[LMAXC];
#pragma unroll
    for (int l = 0; l < LMAXC; ++l) s[l] = 0.0f;

    for (int ci = 0; ci < 32; ++ci) {
        const float* pc = p0 + (size_t)ci * PP;
        float x0 = pc[0];          // q value (record l=0)
        s[0] += x0 * x0;
        for (int l = 1; l < len; ++l) {
            float xl = pc[(size_t)l * CP];
            s[l] += x0 * xl;
        }
    }

    __shared__ float red[LMAXC][8][32];  // [l][c-group][pixel]
    __shared__ float att[LMAXC][32];     // [l][pixel]

    for (int l = 0; l < len; ++l) red[l][grp][pxl] = s[l];
    __syncthreads();

    // ---- Softmax over l, one thread per pixel ----
    if (tid < 32) {
        float sc[LMAXC];
        float m = -1e30f;
        for (int l = 0; l < len; ++l) {
            float v = 0.0f;
#pragma unroll
            for (int g = 0; g < 8; ++g) v += red[l][g][tid];
            v *= 0.0625f;   // 1/sqrt(256)
            sc[l] = v;
            m = fmaxf(m, v);
        }
        float sum = 0.0f;
        for (int l = 0; l < len; ++l) { sc[l] = __expf(sc[l] - m); sum += sc[l]; }
        float inv = 1.0f / sum;
#pragma unroll
        for (int l = 0; l < LMAXC; ++l)
            att[l][tid] = (l < len) ? sc[l] * inv : 0.0f;
    }
    __syncthreads();

    // ---- Pass 2: weighted sum over l, re-reading the tile ----
    float a[LMAXC];
#pragma unroll
    for (int l = 0; l < LMAXC; ++l) a[l] = att[l][pxl];

    float* op = out + (size_t)b * CP + (size_t)c0 * PP + (size_t)px;
    for (int ci = 0; ci < 32; ++ci) {
        const float* pc = p0 + (size_t)ci * PP;
        float acc = a[0] * pc[0];
        for (int l = 1; l < len; ++l) acc += a[l] * pc[(size_t)l * CP];
        op[(size_t)ci * PP] = acc;
    }
}

extern "C" void kernel_launch(void* const* d_in, const int* in_sizes, int n_in,
                              void* d_out, int out_size, void* d_ws, size_t ws_size,
                              hipStream_t stream) {
    const float* x  = (const float*)d_in[0];
    const int*   rl = (const int*)d_in[1];
    float*       out = (float*)d_out;
    const int B = in_sizes[1];          // 4
    dim3 grid(PP / 32, B);              // 864 x 4 = 3456 blocks
    attfusion_kernel<<<grid, 256, 0, stream>>>(x, rl, out);
}

// Round 2
// 712.992 us; speedup vs baseline: 1.1115x; 1.1115x over previous
//
#include <hip/hip_runtime.h>

// AttFusion: per-pixel attention over L<=6 records.
// x: (16, 256, 96*288) fp32, record_len: (4,) int32, out: (4, 256, 96*288) fp32.
//
// R2: float4 loads (16B/lane) + template<LEN> so both passes fully unroll.
// Block = (batch, 32 float4-pixel tile = 128 px), 256 thr = 32 px4 x 8 c-groups.
// Pass 1: partial scores -> LDS reduce -> softmax. Pass 2: cache-served re-read,
// weighted sum, coalesced float4 stores. R1 counters: FETCH=1x x (re-read hits
// cache), 1.65 TB/s, VALU 15% -> latency-bound on scalar loads.

#define CC 256
#define PP (96 * 288)        // 27648
#define P4 (PP / 4)          // 6912 float4 per (record,channel) row
#define LMAXC 6

template <int LEN>
__device__ __forceinline__ void att_body(
    const float4* __restrict__ xbase,   // x + off*CP4 + c0*P4 + px4
    float4* __restrict__ obase,         // out + b*CP4 + c0*P4 + px4
    float4 (&red)[LMAXC][8][32],
    float4 (&att)[LMAXC][32],
    int pxl, int grp, int tid)
{
    const size_t CP4 = (size_t)CC * P4;

    // ---- Pass 1: partial scores over this thread's 32 channels ----
    float4 s[LEN];
#pragma unroll
    for (int l = 0; l < LEN; ++l) s[l] = make_float4(0.f, 0.f, 0.f, 0.f);

#pragma unroll 4
    for (int ci = 0; ci < 32; ++ci) {
        const size_t o = (size_t)ci * P4;
        float4 x0 = xbase[o];
        s[0].x = fmaf(x0.x, x0.x, s[0].x);
        s[0].y = fmaf(x0.y, x0.y, s[0].y);
        s[0].z = fmaf(x0.z, x0.z, s[0].z);
        s[0].w = fmaf(x0.w, x0.w, s[0].w);
#pragma unroll
        for (int l = 1; l < LEN; ++l) {
            float4 xl = xbase[o + (size_t)l * CP4];
            s[l].x = fmaf(x0.x, xl.x, s[l].x);
            s[l].y = fmaf(x0.y, xl.y, s[l].y);
            s[l].z = fmaf(x0.z, xl.z, s[l].z);
            s[l].w = fmaf(x0.w, xl.w, s[l].w);
        }
    }

#pragma unroll
    for (int l = 0; l < LEN; ++l) red[l][grp][pxl] = s[l];
    __syncthreads();

    // ---- Softmax over l, one thread per float4 of pixels ----
    if (tid < 32) {
        float4 v[LEN];
#pragma unroll
        for (int l = 0; l < LEN; ++l) {
            float4 a = make_float4(0.f, 0.f, 0.f, 0.f);
#pragma unroll
            for (int g = 0; g < 8; ++g) {
                float4 r = red[l][g][tid];
                a.x += r.x; a.y += r.y; a.z += r.z; a.w += r.w;
            }
            v[l] = make_float4(a.x * 0.0625f, a.y * 0.0625f,
                               a.z * 0.0625f, a.w * 0.0625f);
        }
        float4 m = v[0];
#pragma unroll
        for (int l = 1; l < LEN; ++l) {
            m.x = fmaxf(m.x, v[l].x); m.y = fmaxf(m.y, v[l].y);
            m.z = fmaxf(m.z, v[l].z); m.w = fmaxf(m.w, v[l].w);
        }
        float4 sum = make_float4(0.f, 0.f, 0.f, 0.f);
#pragma unroll
        for (int l = 0; l < LEN; ++l) {
            v[l].x = __expf(v[l].x - m.x); sum.x += v[l].x;
            v[l].y = __expf(v[l].y - m.y); sum.y += v[l].y;
            v[l].z = __expf(v[l].z - m.z); sum.z += v[l].z;
            v[l].w = __expf(v[l].w - m.w); sum.w += v[l].w;
        }
        float4 inv = make_float4(1.f / sum.x, 1.f / sum.y,
                                 1.f / sum.z, 1.f / sum.w);
#pragma unroll
        for (int l = 0; l < LEN; ++l)
            att[l][tid] = make_float4(v[l].x * inv.x, v[l].y * inv.y,
                                      v[l].z * inv.z, v[l].w * inv.w);
    }
    __syncthreads();

    // ---- Pass 2: weighted sum over l, re-reading the tile (cache-served) ----
    float4 a[LEN];
#pragma unroll
    for (int l = 0; l < LEN; ++l) a[l] = att[l][pxl];

#pragma unroll 4
    for (int ci = 0; ci < 32; ++ci) {
        const size_t o = (size_t)ci * P4;
        float4 x0 = xbase[o];
        float4 acc;
        acc.x = a[0].x * x0.x; acc.y = a[0].y * x0.y;
        acc.z = a[0].z * x0.z; acc.w = a[0].w * x0.w;
#pragma unroll
        for (int l = 1; l < LEN; ++l) {
            float4 xl = xbase[o + (size_t)l * CP4];
            acc.x = fmaf(a[l].x, xl.x, acc.x);
            acc.y = fmaf(a[l].y, xl.y, acc.y);
            acc.z = fmaf(a[l].z, xl.z, acc.z);
            acc.w = fmaf(a[l].w, xl.w, acc.w);
        }
        obase[o] = acc;
    }
}

__global__ __launch_bounds__(256) void attfusion_kernel(
    const float4* __restrict__ x, const int* __restrict__ rl,
    float4* __restrict__ out)
{
    __shared__ float4 red[LMAXC][8][32];
    __shared__ float4 att[LMAXC][32];

    const int tid  = threadIdx.x;
    const int pxl  = tid & 31;    // float4-pixel lane within tile
    const int grp  = tid >> 5;    // c-group 0..7 (32 channels each)
    const int tile = blockIdx.x;  // 0..215
    const int b    = blockIdx.y;  // batch
    const int px4  = tile * 32 + pxl;
    const int c0   = grp * 32;

    int off = 0;
    for (int i = 0; i < b; ++i) off += rl[i];
    int len = rl[b];
    if (len > LMAXC) len = LMAXC;
    if (len < 1)     len = 1;

    const size_t CP4 = (size_t)CC * P4;
    const float4* xbase = x   + (size_t)off * CP4 + (size_t)c0 * P4 + px4;
    float4*       obase = out + (size_t)b   * CP4 + (size_t)c0 * P4 + px4;

    switch (len) {
        case 1: att_body<1>(xbase, obase, red, att, pxl, grp, tid); break;
        case 2: att_body<2>(xbase, obase, red, att, pxl, grp, tid); break;
        case 3: att_body<3>(xbase, obase, red, att, pxl, grp, tid); break;
        case 4: att_body<4>(xbase, obase, red, att, pxl, grp, tid); break;
        case 5: att_body<5>(xbase, obase, red, att, pxl, grp, tid); break;
        default: att_body<6>(xbase, obase, red, att, pxl, grp, tid); break;
    }
}

extern "C" void kernel_launch(void* const* d_in, const int* in_sizes, int n_in,
                              void* d_out, int out_size, void* d_ws, size_t ws_size,
                              hipStream_t stream) {
    const float4* x  = (const float4*)d_in[0];
    const int*    rl = (const int*)d_in[1];
    float4*       out = (float4*)d_out;
    const int B = in_sizes[1];          // 4
    dim3 grid(P4 / 32, B);              // 216 x 4 = 864 blocks
    attfusion_kernel<<<grid, 256, 0, stream>>>(x, rl, out);
}